// Round 10
// baseline (329.717 us; speedup 1.0000x reference)
//
#include <hip/hip_runtime.h>

#define B 8
#define F 257
#define C 8
#define T 800
#define TAPS 5
#define DELAY 3
#define K 40         // TAPS*C
#define NCOL 48      // K + C
#define T0 7         // DELAY + TAPS - 1
#define BF (B*F)     // 2056

typedef __bf16 bf16x8 __attribute__((ext_vector_type(8)));
typedef __bf16 bf16x4 __attribute__((ext_vector_type(4)));
typedef float f32x4 __attribute__((ext_vector_type(4)));

// ---------------- kernel 1: sqrt inverse power weights (0 for t<T0) ----------------
__global__ __launch_bounds__(256) void power_kernel(const float* __restrict__ sr,
                                                    const float* __restrict__ si,
                                                    float* __restrict__ W) {
    int bf = blockIdx.x;
    const float* srp = sr + (size_t)bf * C * T;
    const float* sip = si + (size_t)bf * C * T;
    int t0 = threadIdx.x * 4;
    if (t0 < T) {
        float s[4] = {0.f, 0.f, 0.f, 0.f};
#pragma unroll
        for (int c = 0; c < C; ++c) {
            float4 a = *(const float4*)(srp + c * T + t0);
            float4 b = *(const float4*)(sip + c * T + t0);
            s[0] = fmaf(a.x, a.x, fmaf(b.x, b.x, s[0]));
            s[1] = fmaf(a.y, a.y, fmaf(b.y, b.y, s[1]));
            s[2] = fmaf(a.z, a.z, fmaf(b.z, b.z, s[2]));
            s[3] = fmaf(a.w, a.w, fmaf(b.w, b.w, s[3]));
        }
        float4 w;
        float* wp = (float*)&w;
#pragma unroll
        for (int e = 0; e < 4; ++e) {
            float v = fmaxf(s[e] * (1.0f / C), 1e-7f);
            wp[e] = (t0 + e < T0) ? 0.f : rsqrtf(v);   // sqrt(1/power)
        }
        *(float4*)(W + (size_t)bf * T + t0) = w;
    }
}

// ---------------- kernel 2: R,P via bf16 MFMA, sqrt(w)-symmetrized Gram ----------------
#define WB 10624

__global__ __launch_bounds__(256, 3) void rp_mfma_kernel(const float* __restrict__ mr,
                                                         const float* __restrict__ mi,
                                                         const float* __restrict__ W,
                                                         float2* __restrict__ Rout,
                                                         float2* __restrict__ Pout) {
    __shared__ __align__(16) unsigned char SH[4 * WB];
    const int lane = threadIdx.x & 63;
    const int wid = threadIdx.x >> 6;
    const int bf = blockIdx.x * 4 + wid;
    unsigned char* base = SH + wid * WB;
    float* sre = (float*)(base + 7680);
    float* sim_ = (float*)(base + 9088);
    float* wsh = (float*)(base + 10496);

    const float* mrp = mr + (size_t)bf * C * T;
    const float* mip = mi + (size_t)bf * C * T;
    const float* Wp  = W  + (size_t)bf * T;

    const int q = lane >> 4, col = lane & 15;
    const int pc = lane >> 3, pg = lane & 7;     // phase-B task: channel, 4t-group

    const int PM[6] = {0, 0, 0, 1, 1, 2};
    const int PN[6] = {0, 1, 2, 1, 2, 2};

    f32x4 accRe[6], accIr[6], accRi[6];
#pragma unroll
    for (int p = 0; p < 6; ++p) {
        accRe[p] = (f32x4){0.f, 0.f, 0.f, 0.f};
        accIr[p] = (f32x4){0.f, 0.f, 0.f, 0.f};
        accRi[p] = (f32x4){0.f, 0.f, 0.f, 0.f};
    }

    for (int ks = 0; ks < 25; ++ks) {
        const int tb = ks * 32;

        // ---- Phase A: vectorized global -> fp32 LDS scratch ----
#pragma unroll
        for (int it = 0; it < 3; ++it) {
            int task = lane + it * 64;
            if (task < 160) {
                int pl = task / 80;
                int rem = task - pl * 80;
                int c = rem / 10, grp = rem - c * 10;
                int tg = tb - 8 + grp * 4;
                const float* srcp = pl ? mip : mrp;
                float4 v = make_float4(0.f, 0.f, 0.f, 0.f);
                if (tg >= 0) v = *(const float4*)(srcp + c * T + tg);
                *(float4*)((pl ? sim_ : sre) + c * 44 + grp * 4) = v;
            } else if (task < 168) {
                int grp = task - 160;
                *(float4*)(wsh + grp * 4) = *(const float4*)(Wp + tb + grp * 4);
            }
        }

        // ---- Phase B: build 6 shift-variant bf16 rows from scratch ----
        {
            float yre[12], yim[12];
            int ybase = pc * 44 + pg * 4;
#pragma unroll
            for (int i = 1; i <= 11; ++i) {
                yre[i] = sre[ybase + i];
                yim[i] = sim_[ybase + i];
            }
            float4 w4 = *(const float4*)(wsh + pg * 4);
            float wv[4] = {w4.x, w4.y, w4.z, w4.w};
#pragma unroll
            for (int v = 0; v < 6; ++v) {
                int row = (v < 5) ? (v * 8 + pc) : (40 + pc);
                int off = (v < 5) ? (5 - v) : 8;
                bf16x4 zr, zi;
#pragma unroll
                for (int e = 0; e < 4; ++e) {
                    zr[e] = (__bf16)(wv[e] * yre[off + e]);
                    zi[e] = (__bf16)(wv[e] * yim[off + e]);
                }
                *(bf16x4*)(base + row * 80 + pg * 8) = zr;
                *(bf16x4*)(base + 3840 + row * 80 + pg * 8) = zi;
            }
        }

        // ---- fragments (shared A/B operand) + 24 MFMA ----
        bf16x8 fr[3], fi[3];
#pragma unroll
        for (int X = 0; X < 3; ++X) {
            fr[X] = *(const bf16x8*)(base + (X * 16 + col) * 80 + q * 16);
            fi[X] = *(const bf16x8*)(base + 3840 + (X * 16 + col) * 80 + q * 16);
        }
#pragma unroll
        for (int p = 0; p < 6; ++p) {
            int mt = PM[p], nt = PN[p];
            accRe[p] = __builtin_amdgcn_mfma_f32_16x16x32_bf16(fr[mt], fr[nt], accRe[p], 0, 0, 0);
            accRe[p] = __builtin_amdgcn_mfma_f32_16x16x32_bf16(fi[mt], fi[nt], accRe[p], 0, 0, 0);
            accIr[p] = __builtin_amdgcn_mfma_f32_16x16x32_bf16(fi[mt], fr[nt], accIr[p], 0, 0, 0);
            accRi[p] = __builtin_amdgcn_mfma_f32_16x16x32_bf16(fr[mt], fi[nt], accRi[p], 0, 0, 0);
        }
    }

    // ---- epilogue: D row=(lane>>4)*4+reg, col=lane&15 (m89); Hermitian mirror ----
    float2* Rp = Rout + (size_t)bf * K * K;
    float2* Pp = Pout + (size_t)bf * K * C;
#pragma unroll
    for (int p = 0; p < 6; ++p) {
        int mt = PM[p], nt = PN[p];
#pragma unroll
        for (int r = 0; r < 4; ++r) {
            int m = mt * 16 + q * 4 + r;
            int n = nt * 16 + col;
            float re = accRe[p][r];
            float im = accIr[p][r] - accRi[p][r];
            if (m < K) {
                if (n < K) Rp[m * K + n] = make_float2(re, im);
                else       Pp[m * C + (n - K)] = make_float2(re, im);
            }
            if (mt != nt && m < K && n < K)
                Rp[n * K + m] = make_float2(re, -im);
        }
    }
}

// ---------------- kernel 3: solve R G = P — static full-width elimination ----------------
// One wave per bf. aug[40][50] float2 (cols: 0-39 R, 40-47 RHS, 48-49 pad).
// Per step: pivot (shfl reduce) -> b128 row swap -> UNCONDITIONAL full-row update
// in 5 groups of 5 float4 chunks (reads batched -> LDS latency pipelined).
// Full-width is safe: col n only depends on col n; cols<j are dead L-region.
#define SROW 50

__global__ __launch_bounds__(64) void solve_kernel(const float2* __restrict__ Rin,
                                                   const float2* __restrict__ Pin,
                                                   float2* __restrict__ Gout) {
    __shared__ __align__(16) float2 aug[K][SROW];   // 16000 B
    int bf = blockIdx.x;
    int lane = threadIdx.x;

    for (int i = lane; i < K * K; i += 64) {
        int r = i / K, c2 = i % K;
        float2 v = Rin[(size_t)bf * K * K + i];
        if (r == c2) v.x += 1e-10f;
        aug[r][c2] = v;
    }
    for (int i = lane; i < K * C; i += 64)
        aug[i >> 3][K + (i & 7)] = Pin[(size_t)bf * K * C + i];
    if (lane < K * 2)   // zero pad cols 48,49
        aug[lane >> 1][NCOL + (lane & 1)] = make_float2(0.f, 0.f);
    __syncthreads();

    // forward elimination with partial pivoting
    for (int j = 0; j < K; ++j) {
        float mag = -1.0f;
        int idx = lane;
        if (lane >= j && lane < K) {
            float2 v = aug[lane][j];
            mag = fabsf(v.x) + fabsf(v.y);
        }
        for (int off = 32; off; off >>= 1) {
            float om = __shfl_xor(mag, off);
            int oi = __shfl_xor(idx, off);
            if (om > mag || (om == mag && oi < idx)) { mag = om; idx = oi; }
        }
        int piv = idx;
        if (piv != j && lane < SROW / 2) {   // 25 float4 chunks
            float4* rj = (float4*)&aug[j][0];
            float4* rp = (float4*)&aug[piv][0];
            float4 a = rj[lane], b2 = rp[lane];
            rj[lane] = b2; rp[lane] = a;
        }
        __syncthreads();

        float2 d = aug[j][j];
        float den = fmaf(d.x, d.x, d.y * d.y);
        float rden = 1.0f / den;
        float2 invp = make_float2(d.x * rden, -d.y * rden);
        float2 l = make_float2(0.f, 0.f);
        if (lane > j && lane < K) {
            float2 v = aug[lane][j];
            l = make_float2(v.x * invp.x - v.y * invp.y,
                            v.x * invp.y + v.y * invp.x);
        }
        if (lane < K) {
            float4* rowi = (float4*)&aug[lane][0];
            const float4* rowj = (const float4*)&aug[j][0];
#pragma unroll
            for (int g = 0; g < 5; ++g) {
                float4 u[5], a[5];
#pragma unroll
                for (int m = 0; m < 5; ++m) u[m] = rowj[g * 5 + m];
#pragma unroll
                for (int m = 0; m < 5; ++m) a[m] = rowi[g * 5 + m];
#pragma unroll
                for (int m = 0; m < 5; ++m) {
                    // complex pair: (x,y) and (z,w); a -= l*u
                    a[m].x = fmaf(-l.x, u[m].x, fmaf( l.y, u[m].y, a[m].x));
                    a[m].y = fmaf(-l.x, u[m].y, fmaf(-l.y, u[m].x, a[m].y));
                    a[m].z = fmaf(-l.x, u[m].z, fmaf( l.y, u[m].w, a[m].z));
                    a[m].w = fmaf(-l.x, u[m].w, fmaf(-l.y, u[m].z, a[m].w));
                }
#pragma unroll
                for (int m = 0; m < 5; ++m) rowi[g * 5 + m] = a[m];
            }
        }
        __syncthreads();
    }

    // upward substitution on 8 RHS columns; lane = (isub, e)
    int isub = lane >> 3, e = lane & 7;
    for (int j = K - 1; j >= 0; --j) {
        float2 d = aug[j][j];
        float den = fmaf(d.x, d.x, d.y * d.y);
        float rden = 1.0f / den;
        float2 invp = make_float2(d.x * rden, -d.y * rden);
        if (lane < C) {
            float2 v = aug[j][K + lane];
            aug[j][K + lane] = make_float2(v.x * invp.x - v.y * invp.y,
                                           v.x * invp.y + v.y * invp.x);
        }
        __syncthreads();
        float2 xj = aug[j][K + e];
#pragma unroll
        for (int ii = 0; ii < 5; ++ii) {
            int i = isub + 8 * ii;
            if (i < j) {
                float2 u = aug[i][j];
                float2 a = aug[i][K + e];
                a.x = fmaf(-u.x, xj.x, fmaf( u.y, xj.y, a.x));
                a.y = fmaf(-u.x, xj.y, fmaf(-u.y, xj.x, a.y));
                aug[i][K + e] = a;
            }
        }
        __syncthreads();
    }

    for (int i = lane; i < K * C; i += 64)
        Gout[(size_t)bf * K * C + i] = aug[i >> 3][K + (i & 7)];
}

// ---------------- kernel 4: X = Y - G^H Yt — R6 body, 2 chunks of 400 t ----------------
#define TCX 400
#define HALOX 7
#define LX (TCX + HALOX)   // 407

__global__ __launch_bounds__(256) void x_kernel(const float* __restrict__ mr,
                                                const float* __restrict__ mi,
                                                const float2* __restrict__ Gin,
                                                const int* __restrict__ ilens,
                                                float2* __restrict__ out) {
    __shared__ float2 Ysh[C][LX];     // 26048 B
    __shared__ float2 Gsh[K][C];      // 2560 B
    int gid = blockIdx.x;
    int bf = gid >> 1;
    int half = gid & 1;
    int ts = half * TCX;
    int b = bf / F;
    int tid = threadIdx.x;
    const float* mrp = mr + (size_t)bf * C * T;
    const float* mip = mi + (size_t)bf * C * T;

    for (int i = tid; i < C * LX; i += 256) {
        int c = i / LX, l = i - c * LX;
        int tau = ts - HALOX + l;
        Ysh[c][l] = (tau >= 0) ? make_float2(mrp[c * T + tau], mip[c * T + tau])
                               : make_float2(0.f, 0.f);
    }
    for (int i = tid; i < K * C; i += 256)
        Gsh[i >> 3][i & 7] = Gin[(size_t)bf * K * C + i];
    __syncthreads();

    int len = ilens[b];

    float2 acc[2][C];
#pragma unroll
    for (int it = 0; it < 2; ++it) {
        int tt = tid + it * 256;
#pragma unroll
        for (int e = 0; e < C; ++e)
            acc[it][e] = (tt < TCX) ? Ysh[e][tt + HALOX] : make_float2(0.f, 0.f);
    }

#pragma unroll
    for (int k = 0; k < TAPS; ++k) {
#pragma unroll
        for (int c = 0; c < C; ++c) {
            int a = k * C + c;
            float2 g[C];
#pragma unroll
            for (int e = 0; e < C; ++e) g[e] = Gsh[a][e];
#pragma unroll
            for (int it = 0; it < 2; ++it) {
                int tt = tid + it * 256;
                if (tt < TCX) {
                    float2 yt = Ysh[c][tt + HALOX - DELAY - k];
#pragma unroll
                    for (int e = 0; e < C; ++e) {
                        // acc -= conj(g) * yt
                        acc[it][e].x = fmaf(-g[e].x, yt.x, acc[it][e].x);
                        acc[it][e].x = fmaf(-g[e].y, yt.y, acc[it][e].x);
                        acc[it][e].y = fmaf(-g[e].x, yt.y, acc[it][e].y);
                        acc[it][e].y = fmaf(g[e].y, yt.x, acc[it][e].y);
                    }
                }
            }
        }
    }

#pragma unroll
    for (int it = 0; it < 2; ++it) {
        int tt = tid + it * 256;
        if (tt < TCX) {
            int t = ts + tt;
            bool ok = (t < len);
#pragma unroll
            for (int e = 0; e < C; ++e) {
                float2 v = ok ? acc[it][e] : make_float2(0.f, 0.f);
                out[((size_t)bf * C + e) * T + t] = v;
            }
        }
    }
}

extern "C" void kernel_launch(void* const* d_in, const int* in_sizes, int n_in,
                              void* d_out, int out_size, void* d_ws, size_t ws_size,
                              hipStream_t stream) {
    const float* sep_r = (const float*)d_in[0];
    const float* sep_i = (const float*)d_in[1];
    const float* mix_r = (const float*)d_in[2];
    const float* mix_i = (const float*)d_in[3];
    const int* ilens   = (const int*)d_in[4];

    float* ws = (float*)d_ws;
    float* W = ws;                                        // BF*T floats
    float2* Rws = (float2*)(ws + (size_t)BF * T);         // BF*K*K float2
    float2* Gws = Rws + (size_t)BF * K * K;               // BF*K*C float2 (P then G in-place)

    power_kernel<<<BF, 256, 0, stream>>>(sep_r, sep_i, W);
    rp_mfma_kernel<<<BF / 4, 256, 0, stream>>>(mix_r, mix_i, W, Rws, Gws);
    solve_kernel<<<BF, 64, 0, stream>>>(Rws, Gws, Gws);
    x_kernel<<<BF * 2, 256, 0, stream>>>(mix_r, mix_i, Gws, ilens, (float2*)d_out);
}

// Round 11
// 276.398 us; speedup vs baseline: 1.1929x; 1.1929x over previous
//
#include <hip/hip_runtime.h>

#define B 8
#define F 257
#define C 8
#define T 800
#define TAPS 5
#define DELAY 3
#define K 40         // TAPS*C
#define NCOL 48      // K + C
#define T0 7         // DELAY + TAPS - 1
#define BF (B*F)     // 2056

typedef __bf16 bf16x8 __attribute__((ext_vector_type(8)));
typedef __bf16 bf16x4 __attribute__((ext_vector_type(4)));
typedef float f32x4 __attribute__((ext_vector_type(4)));

// ---------------- kernel 1: sqrt inverse power weights (0 for t<T0) ----------------
__global__ __launch_bounds__(256) void power_kernel(const float* __restrict__ sr,
                                                    const float* __restrict__ si,
                                                    float* __restrict__ W) {
    int bf = blockIdx.x;
    const float* srp = sr + (size_t)bf * C * T;
    const float* sip = si + (size_t)bf * C * T;
    int t0 = threadIdx.x * 4;
    if (t0 < T) {
        float s[4] = {0.f, 0.f, 0.f, 0.f};
#pragma unroll
        for (int c = 0; c < C; ++c) {
            float4 a = *(const float4*)(srp + c * T + t0);
            float4 b = *(const float4*)(sip + c * T + t0);
            s[0] = fmaf(a.x, a.x, fmaf(b.x, b.x, s[0]));
            s[1] = fmaf(a.y, a.y, fmaf(b.y, b.y, s[1]));
            s[2] = fmaf(a.z, a.z, fmaf(b.z, b.z, s[2]));
            s[3] = fmaf(a.w, a.w, fmaf(b.w, b.w, s[3]));
        }
        float4 w;
        float* wp = (float*)&w;
#pragma unroll
        for (int e = 0; e < 4; ++e) {
            float v = fmaxf(s[e] * (1.0f / C), 1e-7f);
            wp[e] = (t0 + e < T0) ? 0.f : rsqrtf(v);   // sqrt(1/power)
        }
        *(float4*)(W + (size_t)bf * T + t0) = w;
    }
}

// ---------------- kernel 2: R,P via bf16 MFMA, sqrt(w)-symmetrized Gram ----------------
#define WB 10624

__global__ __launch_bounds__(256, 3) void rp_mfma_kernel(const float* __restrict__ mr,
                                                         const float* __restrict__ mi,
                                                         const float* __restrict__ W,
                                                         float2* __restrict__ Rout,
                                                         float2* __restrict__ Pout) {
    __shared__ __align__(16) unsigned char SH[4 * WB];
    const int lane = threadIdx.x & 63;
    const int wid = threadIdx.x >> 6;
    const int bf = blockIdx.x * 4 + wid;
    unsigned char* base = SH + wid * WB;
    float* sre = (float*)(base + 7680);
    float* sim_ = (float*)(base + 9088);
    float* wsh = (float*)(base + 10496);

    const float* mrp = mr + (size_t)bf * C * T;
    const float* mip = mi + (size_t)bf * C * T;
    const float* Wp  = W  + (size_t)bf * T;

    const int q = lane >> 4, col = lane & 15;
    const int pc = lane >> 3, pg = lane & 7;     // phase-B task: channel, 4t-group

    const int PM[6] = {0, 0, 0, 1, 1, 2};
    const int PN[6] = {0, 1, 2, 1, 2, 2};

    f32x4 accRe[6], accIr[6], accRi[6];
#pragma unroll
    for (int p = 0; p < 6; ++p) {
        accRe[p] = (f32x4){0.f, 0.f, 0.f, 0.f};
        accIr[p] = (f32x4){0.f, 0.f, 0.f, 0.f};
        accRi[p] = (f32x4){0.f, 0.f, 0.f, 0.f};
    }

    for (int ks = 0; ks < 25; ++ks) {
        const int tb = ks * 32;

        // ---- Phase A: vectorized global -> fp32 LDS scratch ----
#pragma unroll
        for (int it = 0; it < 3; ++it) {
            int task = lane + it * 64;
            if (task < 160) {
                int pl = task / 80;
                int rem = task - pl * 80;
                int c = rem / 10, grp = rem - c * 10;
                int tg = tb - 8 + grp * 4;
                const float* srcp = pl ? mip : mrp;
                float4 v = make_float4(0.f, 0.f, 0.f, 0.f);
                if (tg >= 0) v = *(const float4*)(srcp + c * T + tg);
                *(float4*)((pl ? sim_ : sre) + c * 44 + grp * 4) = v;
            } else if (task < 168) {
                int grp = task - 160;
                *(float4*)(wsh + grp * 4) = *(const float4*)(Wp + tb + grp * 4);
            }
        }

        // ---- Phase B: build 6 shift-variant bf16 rows from scratch ----
        {
            float yre[12], yim[12];
            int ybase = pc * 44 + pg * 4;
#pragma unroll
            for (int i = 1; i <= 11; ++i) {
                yre[i] = sre[ybase + i];
                yim[i] = sim_[ybase + i];
            }
            float4 w4 = *(const float4*)(wsh + pg * 4);
            float wv[4] = {w4.x, w4.y, w4.z, w4.w};
#pragma unroll
            for (int v = 0; v < 6; ++v) {
                int row = (v < 5) ? (v * 8 + pc) : (40 + pc);
                int off = (v < 5) ? (5 - v) : 8;
                bf16x4 zr, zi;
#pragma unroll
                for (int e = 0; e < 4; ++e) {
                    zr[e] = (__bf16)(wv[e] * yre[off + e]);
                    zi[e] = (__bf16)(wv[e] * yim[off + e]);
                }
                *(bf16x4*)(base + row * 80 + pg * 8) = zr;
                *(bf16x4*)(base + 3840 + row * 80 + pg * 8) = zi;
            }
        }

        // ---- fragments (shared A/B operand) + 24 MFMA ----
        bf16x8 fr[3], fi[3];
#pragma unroll
        for (int X = 0; X < 3; ++X) {
            fr[X] = *(const bf16x8*)(base + (X * 16 + col) * 80 + q * 16);
            fi[X] = *(const bf16x8*)(base + 3840 + (X * 16 + col) * 80 + q * 16);
        }
#pragma unroll
        for (int p = 0; p < 6; ++p) {
            int mt = PM[p], nt = PN[p];
            accRe[p] = __builtin_amdgcn_mfma_f32_16x16x32_bf16(fr[mt], fr[nt], accRe[p], 0, 0, 0);
            accRe[p] = __builtin_amdgcn_mfma_f32_16x16x32_bf16(fi[mt], fi[nt], accRe[p], 0, 0, 0);
            accIr[p] = __builtin_amdgcn_mfma_f32_16x16x32_bf16(fi[mt], fr[nt], accIr[p], 0, 0, 0);
            accRi[p] = __builtin_amdgcn_mfma_f32_16x16x32_bf16(fr[mt], fi[nt], accRi[p], 0, 0, 0);
        }
    }

    // ---- epilogue: D row=(lane>>4)*4+reg, col=lane&15 (m89); Hermitian mirror ----
    float2* Rp = Rout + (size_t)bf * K * K;
    float2* Pp = Pout + (size_t)bf * K * C;
#pragma unroll
    for (int p = 0; p < 6; ++p) {
        int mt = PM[p], nt = PN[p];
#pragma unroll
        for (int r = 0; r < 4; ++r) {
            int m = mt * 16 + q * 4 + r;
            int n = nt * 16 + col;
            float re = accRe[p][r];
            float im = accIr[p][r] - accRi[p][r];
            if (m < K) {
                if (n < K) Rp[m * K + n] = make_float2(re, im);
                else       Pp[m * C + (n - K)] = make_float2(re, im);
            }
            if (mt != nt && m < K && n < K)
                Rp[n * K + m] = make_float2(re, -im);
        }
    }
}

// ---------------- kernel 3: solve R G = P — UNPIVOTED (R is Hermitian PD) ----------------
// One wave per bf. aug[40][50] float2. Per step: d -> invp -> l -> full-row update in
// float4 groups, skipping groups entirely left of the pivot (dead L-region).
// Upward pass: xj computed redundantly per lane (no normalize round-trip), G written
// directly to Gout as each row finalizes.
#define SROW 50

__global__ __launch_bounds__(64) void solve_kernel(const float2* __restrict__ Rin,
                                                   const float2* __restrict__ Pin,
                                                   float2* __restrict__ Gout) {
    __shared__ __align__(16) float2 aug[K][SROW];   // 16000 B
    int bf = blockIdx.x;
    int lane = threadIdx.x;

    for (int i = lane; i < K * K; i += 64) {
        int r = i / K, c2 = i % K;
        float2 v = Rin[(size_t)bf * K * K + i];
        if (r == c2) v.x += 1e-10f;
        aug[r][c2] = v;
    }
    for (int i = lane; i < K * C; i += 64)
        aug[i >> 3][K + (i & 7)] = Pin[(size_t)bf * K * C + i];
    if (lane < K * 2)   // zero pad cols 48,49
        aug[lane >> 1][NCOL + (lane & 1)] = make_float2(0.f, 0.f);
    __syncthreads();

    // forward elimination, no pivoting
    for (int j = 0; j < K; ++j) {
        float2 d = aug[j][j];
        float den = fmaf(d.x, d.x, d.y * d.y);
        float rden = 1.0f / den;
        float2 invp = make_float2(d.x * rden, -d.y * rden);
        float2 l = make_float2(0.f, 0.f);
        if (lane > j && lane < K) {
            float2 v = aug[lane][j];
            l = make_float2(v.x * invp.x - v.y * invp.y,
                            v.x * invp.y + v.y * invp.x);
        }
        if (lane < K) {
            float4* rowi = (float4*)&aug[lane][0];
            const float4* rowj = (const float4*)&aug[j][0];
#pragma unroll
            for (int g = 0; g < 5; ++g) {
                // group g covers complex cols [10g, 10g+10); dead once j > 10g+9
                if (j <= 10 * g + 9) {
                    float4 u[5], a[5];
#pragma unroll
                    for (int m = 0; m < 5; ++m) u[m] = rowj[g * 5 + m];
#pragma unroll
                    for (int m = 0; m < 5; ++m) a[m] = rowi[g * 5 + m];
#pragma unroll
                    for (int m = 0; m < 5; ++m) {
                        a[m].x = fmaf(-l.x, u[m].x, fmaf( l.y, u[m].y, a[m].x));
                        a[m].y = fmaf(-l.x, u[m].y, fmaf(-l.y, u[m].x, a[m].y));
                        a[m].z = fmaf(-l.x, u[m].z, fmaf( l.y, u[m].w, a[m].z));
                        a[m].w = fmaf(-l.x, u[m].w, fmaf(-l.y, u[m].z, a[m].w));
                    }
#pragma unroll
                    for (int m = 0; m < 5; ++m) rowi[g * 5 + m] = a[m];
                }
            }
        }
        __syncthreads();
    }

    // upward substitution; lane = (isub = lane>>3, e = lane&7)
    float2* Gp = Gout + (size_t)bf * K * C;
    int isub = lane >> 3, e = lane & 7;
    for (int j = K - 1; j >= 0; --j) {
        float2 d = aug[j][j];
        float den = fmaf(d.x, d.x, d.y * d.y);
        float rden = 1.0f / den;
        float2 invp = make_float2(d.x * rden, -d.y * rden);
        // every lane computes xj for its e (redundant across isub, broadcast reads)
        float2 xr = aug[j][K + e];
        float2 xj = make_float2(xr.x * invp.x - xr.y * invp.y,
                                xr.x * invp.y + xr.y * invp.x);
        if (isub == 0)   // 8 lanes write final G row j
            Gp[j * C + e] = xj;
#pragma unroll
        for (int ii = 0; ii < 5; ++ii) {
            int i = isub + 8 * ii;
            if (i < j) {
                float2 u = aug[i][j];
                float2 a = aug[i][K + e];
                a.x = fmaf(-u.x, xj.x, fmaf( u.y, xj.y, a.x));
                a.y = fmaf(-u.x, xj.y, fmaf(-u.y, xj.x, a.y));
                aug[i][K + e] = a;
            }
        }
        __syncthreads();
    }
}

// ---------------- kernel 4: X = Y - G^H Yt — R6 body, 2 chunks of 400 t ----------------
#define TCX 400
#define HALOX 7
#define LX (TCX + HALOX)   // 407

__global__ __launch_bounds__(256) void x_kernel(const float* __restrict__ mr,
                                                const float* __restrict__ mi,
                                                const float2* __restrict__ Gin,
                                                const int* __restrict__ ilens,
                                                float2* __restrict__ out) {
    __shared__ float2 Ysh[C][LX];     // 26048 B
    __shared__ float2 Gsh[K][C];      // 2560 B
    int gid = blockIdx.x;
    int bf = gid >> 1;
    int half = gid & 1;
    int ts = half * TCX;
    int b = bf / F;
    int tid = threadIdx.x;
    const float* mrp = mr + (size_t)bf * C * T;
    const float* mip = mi + (size_t)bf * C * T;

    for (int i = tid; i < C * LX; i += 256) {
        int c = i / LX, l = i - c * LX;
        int tau = ts - HALOX + l;
        Ysh[c][l] = (tau >= 0) ? make_float2(mrp[c * T + tau], mip[c * T + tau])
                               : make_float2(0.f, 0.f);
    }
    for (int i = tid; i < K * C; i += 256)
        Gsh[i >> 3][i & 7] = Gin[(size_t)bf * K * C + i];
    __syncthreads();

    int len = ilens[b];

    float2 acc[2][C];
#pragma unroll
    for (int it = 0; it < 2; ++it) {
        int tt = tid + it * 256;
#pragma unroll
        for (int e = 0; e < C; ++e)
            acc[it][e] = (tt < TCX) ? Ysh[e][tt + HALOX] : make_float2(0.f, 0.f);
    }

#pragma unroll
    for (int k = 0; k < TAPS; ++k) {
#pragma unroll
        for (int c = 0; c < C; ++c) {
            int a = k * C + c;
            float2 g[C];
#pragma unroll
            for (int e = 0; e < C; ++e) g[e] = Gsh[a][e];
#pragma unroll
            for (int it = 0; it < 2; ++it) {
                int tt = tid + it * 256;
                if (tt < TCX) {
                    float2 yt = Ysh[c][tt + HALOX - DELAY - k];
#pragma unroll
                    for (int e = 0; e < C; ++e) {
                        // acc -= conj(g) * yt
                        acc[it][e].x = fmaf(-g[e].x, yt.x, acc[it][e].x);
                        acc[it][e].x = fmaf(-g[e].y, yt.y, acc[it][e].x);
                        acc[it][e].y = fmaf(-g[e].x, yt.y, acc[it][e].y);
                        acc[it][e].y = fmaf(g[e].y, yt.x, acc[it][e].y);
                    }
                }
            }
        }
    }

#pragma unroll
    for (int it = 0; it < 2; ++it) {
        int tt = tid + it * 256;
        if (tt < TCX) {
            int t = ts + tt;
            bool ok = (t < len);
#pragma unroll
            for (int e = 0; e < C; ++e) {
                float2 v = ok ? acc[it][e] : make_float2(0.f, 0.f);
                out[((size_t)bf * C + e) * T + t] = v;
            }
        }
    }
}

extern "C" void kernel_launch(void* const* d_in, const int* in_sizes, int n_in,
                              void* d_out, int out_size, void* d_ws, size_t ws_size,
                              hipStream_t stream) {
    const float* sep_r = (const float*)d_in[0];
    const float* sep_i = (const float*)d_in[1];
    const float* mix_r = (const float*)d_in[2];
    const float* mix_i = (const float*)d_in[3];
    const int* ilens   = (const int*)d_in[4];

    float* ws = (float*)d_ws;
    float* W = ws;                                        // BF*T floats
    float2* Rws = (float2*)(ws + (size_t)BF * T);         // BF*K*K float2
    float2* Gws = Rws + (size_t)BF * K * K;               // BF*K*C float2 (P then G in-place)

    power_kernel<<<BF, 256, 0, stream>>>(sep_r, sep_i, W);
    rp_mfma_kernel<<<BF / 4, 256, 0, stream>>>(mix_r, mix_i, W, Rws, Gws);
    solve_kernel<<<BF, 64, 0, stream>>>(Rws, Gws, Gws);
    x_kernel<<<BF * 2, 256, 0, stream>>>(mix_r, mix_i, Gws, ilens, (float2*)d_out);
}

// Round 12
// 216.770 us; speedup vs baseline: 1.5210x; 1.2751x over previous
//
#include <hip/hip_runtime.h>

#define B 8
#define F 257
#define C 8
#define T 800
#define TAPS 5
#define DELAY 3
#define K 40         // TAPS*C
#define NCOL 48      // K + C
#define T0 7         // DELAY + TAPS - 1
#define BF (B*F)     // 2056

typedef __bf16 bf16x8 __attribute__((ext_vector_type(8)));
typedef __bf16 bf16x4 __attribute__((ext_vector_type(4)));
typedef float f32x4 __attribute__((ext_vector_type(4)));

// ---------------- kernel 1: sqrt inverse power weights (0 for t<T0) ----------------
__global__ __launch_bounds__(256) void power_kernel(const float* __restrict__ sr,
                                                    const float* __restrict__ si,
                                                    float* __restrict__ W) {
    int bf = blockIdx.x;
    const float* srp = sr + (size_t)bf * C * T;
    const float* sip = si + (size_t)bf * C * T;
    int t0 = threadIdx.x * 4;
    if (t0 < T) {
        float s[4] = {0.f, 0.f, 0.f, 0.f};
#pragma unroll
        for (int c = 0; c < C; ++c) {
            float4 a = *(const float4*)(srp + c * T + t0);
            float4 b = *(const float4*)(sip + c * T + t0);
            s[0] = fmaf(a.x, a.x, fmaf(b.x, b.x, s[0]));
            s[1] = fmaf(a.y, a.y, fmaf(b.y, b.y, s[1]));
            s[2] = fmaf(a.z, a.z, fmaf(b.z, b.z, s[2]));
            s[3] = fmaf(a.w, a.w, fmaf(b.w, b.w, s[3]));
        }
        float4 w;
        float* wp = (float*)&w;
#pragma unroll
        for (int e = 0; e < 4; ++e) {
            float v = fmaxf(s[e] * (1.0f / C), 1e-7f);
            wp[e] = (t0 + e < T0) ? 0.f : rsqrtf(v);   // sqrt(1/power)
        }
        *(float4*)(W + (size_t)bf * T + t0) = w;
    }
}

// ---------------- kernel 2: R,P via bf16 MFMA, sqrt(w)-symmetrized Gram ----------------
#define WB 10624

__global__ __launch_bounds__(256, 3) void rp_mfma_kernel(const float* __restrict__ mr,
                                                         const float* __restrict__ mi,
                                                         const float* __restrict__ W,
                                                         float2* __restrict__ Rout,
                                                         float2* __restrict__ Pout) {
    __shared__ __align__(16) unsigned char SH[4 * WB];
    const int lane = threadIdx.x & 63;
    const int wid = threadIdx.x >> 6;
    const int bf = blockIdx.x * 4 + wid;
    unsigned char* base = SH + wid * WB;
    float* sre = (float*)(base + 7680);
    float* sim_ = (float*)(base + 9088);
    float* wsh = (float*)(base + 10496);

    const float* mrp = mr + (size_t)bf * C * T;
    const float* mip = mi + (size_t)bf * C * T;
    const float* Wp  = W  + (size_t)bf * T;

    const int q = lane >> 4, col = lane & 15;
    const int pc = lane >> 3, pg = lane & 7;     // phase-B task: channel, 4t-group

    const int PM[6] = {0, 0, 0, 1, 1, 2};
    const int PN[6] = {0, 1, 2, 1, 2, 2};

    f32x4 accRe[6], accIr[6], accRi[6];
#pragma unroll
    for (int p = 0; p < 6; ++p) {
        accRe[p] = (f32x4){0.f, 0.f, 0.f, 0.f};
        accIr[p] = (f32x4){0.f, 0.f, 0.f, 0.f};
        accRi[p] = (f32x4){0.f, 0.f, 0.f, 0.f};
    }

    for (int ks = 0; ks < 25; ++ks) {
        const int tb = ks * 32;

        // ---- Phase A: vectorized global -> fp32 LDS scratch ----
#pragma unroll
        for (int it = 0; it < 3; ++it) {
            int task = lane + it * 64;
            if (task < 160) {
                int pl = task / 80;
                int rem = task - pl * 80;
                int c = rem / 10, grp = rem - c * 10;
                int tg = tb - 8 + grp * 4;
                const float* srcp = pl ? mip : mrp;
                float4 v = make_float4(0.f, 0.f, 0.f, 0.f);
                if (tg >= 0) v = *(const float4*)(srcp + c * T + tg);
                *(float4*)((pl ? sim_ : sre) + c * 44 + grp * 4) = v;
            } else if (task < 168) {
                int grp = task - 160;
                *(float4*)(wsh + grp * 4) = *(const float4*)(Wp + tb + grp * 4);
            }
        }

        // ---- Phase B: build 6 shift-variant bf16 rows from scratch ----
        {
            float yre[12], yim[12];
            int ybase = pc * 44 + pg * 4;
#pragma unroll
            for (int i = 1; i <= 11; ++i) {
                yre[i] = sre[ybase + i];
                yim[i] = sim_[ybase + i];
            }
            float4 w4 = *(const float4*)(wsh + pg * 4);
            float wv[4] = {w4.x, w4.y, w4.z, w4.w};
#pragma unroll
            for (int v = 0; v < 6; ++v) {
                int row = (v < 5) ? (v * 8 + pc) : (40 + pc);
                int off = (v < 5) ? (5 - v) : 8;
                bf16x4 zr, zi;
#pragma unroll
                for (int e = 0; e < 4; ++e) {
                    zr[e] = (__bf16)(wv[e] * yre[off + e]);
                    zi[e] = (__bf16)(wv[e] * yim[off + e]);
                }
                *(bf16x4*)(base + row * 80 + pg * 8) = zr;
                *(bf16x4*)(base + 3840 + row * 80 + pg * 8) = zi;
            }
        }

        // ---- fragments (shared A/B operand) + 24 MFMA ----
        bf16x8 fr[3], fi[3];
#pragma unroll
        for (int X = 0; X < 3; ++X) {
            fr[X] = *(const bf16x8*)(base + (X * 16 + col) * 80 + q * 16);
            fi[X] = *(const bf16x8*)(base + 3840 + (X * 16 + col) * 80 + q * 16);
        }
#pragma unroll
        for (int p = 0; p < 6; ++p) {
            int mt = PM[p], nt = PN[p];
            accRe[p] = __builtin_amdgcn_mfma_f32_16x16x32_bf16(fr[mt], fr[nt], accRe[p], 0, 0, 0);
            accRe[p] = __builtin_amdgcn_mfma_f32_16x16x32_bf16(fi[mt], fi[nt], accRe[p], 0, 0, 0);
            accIr[p] = __builtin_amdgcn_mfma_f32_16x16x32_bf16(fi[mt], fr[nt], accIr[p], 0, 0, 0);
            accRi[p] = __builtin_amdgcn_mfma_f32_16x16x32_bf16(fr[mt], fi[nt], accRi[p], 0, 0, 0);
        }
    }

    // ---- epilogue: D row=(lane>>4)*4+reg, col=lane&15 (m89); Hermitian mirror ----
    // EPS_REG added on the diagonal here (solve no longer stages through LDS).
    float2* Rp = Rout + (size_t)bf * K * K;
    float2* Pp = Pout + (size_t)bf * K * C;
#pragma unroll
    for (int p = 0; p < 6; ++p) {
        int mt = PM[p], nt = PN[p];
#pragma unroll
        for (int r = 0; r < 4; ++r) {
            int m = mt * 16 + q * 4 + r;
            int n = nt * 16 + col;
            float re = accRe[p][r];
            float im = accIr[p][r] - accRi[p][r];
            if (m < K) {
                if (n < K) {
                    if (m == n) re += 1e-10f;
                    Rp[m * K + n] = make_float2(re, im);
                } else {
                    Pp[m * C + (n - K)] = make_float2(re, im);
                }
            }
            if (mt != nt && m < K && n < K)
                Rp[n * K + m] = make_float2(re, -im);
        }
    }
}

// ---------------- kernel 3: solve R G = P — register-row Gauss-Jordan, ZERO LDS ----------------
// One wave per bf. Lane i holds row i of [R | P] in 48 float2 registers (statically
// indexed via full unroll). Per step j: broadcast lane j's row through v_readlane
// (uniform -> SGPR); l = row[j]*invd, with l_j = 1-invd making the uniform update
// "row -= l*u" normalize row j and eliminate everywhere else. No LDS, no barriers,
// no back-substitution. Lanes 40-63 carry zero rows (l=0 automatically).
__device__ __forceinline__ float rdlane(float v, int j) {
    return __uint_as_float(__builtin_amdgcn_readlane(__float_as_uint(v), (unsigned)j));
}

__global__ __launch_bounds__(64) void solve_kernel(const float2* __restrict__ Rin,
                                                   const float2* __restrict__ Pin,
                                                   float2* __restrict__ Gout) {
    const int bf = blockIdx.x;
    const int lane = threadIdx.x;
    const bool act = lane < K;

    float2 row[NCOL];
    {
        const float4* Rp4 = (const float4*)(Rin + (size_t)bf * K * K + (size_t)(act ? lane : 0) * K);
        const float4* Pp4 = (const float4*)(Pin + (size_t)bf * K * C + (size_t)(act ? lane : 0) * C);
#pragma unroll
        for (int m = 0; m < K / 2; ++m) {
            float4 v = Rp4[m];
            if (!act) v = make_float4(0.f, 0.f, 0.f, 0.f);
            row[2 * m]     = make_float2(v.x, v.y);
            row[2 * m + 1] = make_float2(v.z, v.w);
        }
#pragma unroll
        for (int m = 0; m < C / 2; ++m) {
            float4 v = Pp4[m];
            if (!act) v = make_float4(0.f, 0.f, 0.f, 0.f);
            row[K + 2 * m]     = make_float2(v.x, v.y);
            row[K + 2 * m + 1] = make_float2(v.z, v.w);
        }
    }

#pragma unroll
    for (int j = 0; j < K; ++j) {
        // uniform pivot d = A[j][j]
        float dx = rdlane(row[j].x, j);
        float dy = rdlane(row[j].y, j);
        float den = fmaf(dx, dx, dy * dy);
        float r = 1.0f / den;
        float ix = dx * r;          // invd = conj(d)/|d|^2
        float iy = -dy * r;
        // multiplier: l = row[j]*invd; lane j: l = 1 - invd
        float lx = row[j].x * ix - row[j].y * iy;
        float ly = row[j].x * iy + row[j].y * ix;
        bool isj = (lane == j);
        lx = isj ? (1.0f - ix) : lx;
        ly = isj ? (0.0f - iy) : ly;
#pragma unroll
        for (int n = j; n < NCOL; ++n) {
            float ux = rdlane(row[n].x, j);
            float uy = rdlane(row[n].y, j);
            // row[n] -= l * u
            row[n].x = fmaf(-lx, ux, fmaf( ly, uy, row[n].x));
            row[n].y = fmaf(-lx, uy, fmaf(-ly, ux, row[n].y));
        }
    }

    if (act) {
        float4* Gp = (float4*)(Gout + (size_t)bf * K * C + (size_t)lane * C);
#pragma unroll
        for (int m = 0; m < C / 2; ++m)
            Gp[m] = make_float4(row[K + 2 * m].x, row[K + 2 * m].y,
                                row[K + 2 * m + 1].x, row[K + 2 * m + 1].y);
    }
}

// ---------------- kernel 4: X = Y - G^H Yt — R6 body, 2 chunks of 400 t ----------------
#define TCX 400
#define HALOX 7
#define LX (TCX + HALOX)   // 407

__global__ __launch_bounds__(256) void x_kernel(const float* __restrict__ mr,
                                                const float* __restrict__ mi,
                                                const float2* __restrict__ Gin,
                                                const int* __restrict__ ilens,
                                                float2* __restrict__ out) {
    __shared__ float2 Ysh[C][LX];     // 26048 B
    __shared__ float2 Gsh[K][C];      // 2560 B
    int gid = blockIdx.x;
    int bf = gid >> 1;
    int half = gid & 1;
    int ts = half * TCX;
    int b = bf / F;
    int tid = threadIdx.x;
    const float* mrp = mr + (size_t)bf * C * T;
    const float* mip = mi + (size_t)bf * C * T;

    for (int i = tid; i < C * LX; i += 256) {
        int c = i / LX, l = i - c * LX;
        int tau = ts - HALOX + l;
        Ysh[c][l] = (tau >= 0) ? make_float2(mrp[c * T + tau], mip[c * T + tau])
                               : make_float2(0.f, 0.f);
    }
    for (int i = tid; i < K * C; i += 256)
        Gsh[i >> 3][i & 7] = Gin[(size_t)bf * K * C + i];
    __syncthreads();

    int len = ilens[b];

    float2 acc[2][C];
#pragma unroll
    for (int it = 0; it < 2; ++it) {
        int tt = tid + it * 256;
#pragma unroll
        for (int e = 0; e < C; ++e)
            acc[it][e] = (tt < TCX) ? Ysh[e][tt + HALOX] : make_float2(0.f, 0.f);
    }

#pragma unroll
    for (int k = 0; k < TAPS; ++k) {
#pragma unroll
        for (int c = 0; c < C; ++c) {
            int a = k * C + c;
            float2 g[C];
#pragma unroll
            for (int e = 0; e < C; ++e) g[e] = Gsh[a][e];
#pragma unroll
            for (int it = 0; it < 2; ++it) {
                int tt = tid + it * 256;
                if (tt < TCX) {
                    float2 yt = Ysh[c][tt + HALOX - DELAY - k];
#pragma unroll
                    for (int e = 0; e < C; ++e) {
                        // acc -= conj(g) * yt
                        acc[it][e].x = fmaf(-g[e].x, yt.x, acc[it][e].x);
                        acc[it][e].x = fmaf(-g[e].y, yt.y, acc[it][e].x);
                        acc[it][e].y = fmaf(-g[e].x, yt.y, acc[it][e].y);
                        acc[it][e].y = fmaf(g[e].y, yt.x, acc[it][e].y);
                    }
                }
            }
        }
    }

#pragma unroll
    for (int it = 0; it < 2; ++it) {
        int tt = tid + it * 256;
        if (tt < TCX) {
            int t = ts + tt;
            bool ok = (t < len);
#pragma unroll
            for (int e = 0; e < C; ++e) {
                float2 v = ok ? acc[it][e] : make_float2(0.f, 0.f);
                out[((size_t)bf * C + e) * T + t] = v;
            }
        }
    }
}

extern "C" void kernel_launch(void* const* d_in, const int* in_sizes, int n_in,
                              void* d_out, int out_size, void* d_ws, size_t ws_size,
                              hipStream_t stream) {
    const float* sep_r = (const float*)d_in[0];
    const float* sep_i = (const float*)d_in[1];
    const float* mix_r = (const float*)d_in[2];
    const float* mix_i = (const float*)d_in[3];
    const int* ilens   = (const int*)d_in[4];

    float* ws = (float*)d_ws;
    float* W = ws;                                        // BF*T floats
    float2* Rws = (float2*)(ws + (size_t)BF * T);         // BF*K*K float2
    float2* Gws = Rws + (size_t)BF * K * K;               // BF*K*C float2 (P then G in-place)

    power_kernel<<<BF, 256, 0, stream>>>(sep_r, sep_i, W);
    rp_mfma_kernel<<<BF / 4, 256, 0, stream>>>(mix_r, mix_i, W, Rws, Gws);
    solve_kernel<<<BF, 64, 0, stream>>>(Rws, Gws, Gws);
    x_kernel<<<BF * 2, 256, 0, stream>>>(mix_r, mix_i, Gws, ilens, (float2*)d_out);
}